// Round 4
// baseline (371.539 us; speedup 1.0000x reference)
//
#include <hip/hip_runtime.h>
#include <cstdint>
#include <cmath>

#define T_TOK 1024
#define H_DIM 1024
#define E_NUM 32
#define I_DIM 512
#define IS_DIM 2048
#define NCOL_R 16384
#define NCOL_T 18432
#define SCALE_F 2.5f
#define MAXTILES 96

typedef __bf16 bf16x8 __attribute__((ext_vector_type(8)));
typedef float f32x4 __attribute__((ext_vector_type(4)));

typedef __attribute__((address_space(3))) unsigned int lds_u32_t;
typedef __attribute__((address_space(1))) const unsigned int glb_u32_t;

__device__ __forceinline__ unsigned short f2b(float f) {
    union { float f; uint32_t u; } v; v.f = f;
    return (unsigned short)((v.u + 0x7FFFu + ((v.u >> 16) & 1u)) >> 16);
}

__device__ __forceinline__ void gll16(const unsigned short* g, unsigned short* l) {
    __builtin_amdgcn_global_load_lds((glb_u32_t*)g, (lds_u32_t*)l, 16, 0, 0);
}

// ================= lane-parallel routing: one wave per token =================
__device__ __forceinline__ void routing_wave(const float* __restrict__ x,
                                             const float* __restrict__ gate_w,
                                             const float* __restrict__ e_bias,
                                             float* __restrict__ combine,
                                             int* __restrict__ topk, int t) {
    int l = threadIdx.x & 63;
    int e = l & 31, half = l >> 5;
    const float4* xr = reinterpret_cast<const float4*>(x + (size_t)t * H_DIM + half * 512);
    const float4* wr = reinterpret_cast<const float4*>(gate_w + (size_t)e * H_DIM + half * 512);
    float s = 0.f;
#pragma unroll 8
    for (int j = 0; j < 128; j++) {
        float4 a = xr[j], b = wr[j];
        s += a.x * b.x + a.y * b.y + a.z * b.z + a.w * b.w;
    }
    s += __shfl_xor(s, 32);            // lanes 0..31 (dup in 32..63) hold logit[e]
    float sg = 1.f / (1.f + expf(-s));
    float swb = sg + e_bias[e];
    // group top-2 sum (group = 4 consecutive experts; pairing-invariant formula)
    float v1 = __shfl_xor(swb, 1), v2 = __shfl_xor(swb, 2), v3 = __shfl_xor(swb, 3);
    float hi01 = fmaxf(swb, v1), lo01 = fminf(swb, v1);
    float hi23 = fmaxf(v2, v3),  lo23 = fminf(v2, v3);
    float gs = fmaxf(hi01, hi23) + fmaxf(fminf(hi01, hi23), fmaxf(lo01, lo23));
    int g = e >> 2;
    int grank = 0;
#pragma unroll
    for (int gg = 0; gg < 8; gg++) {
        float og = __shfl(gs, gg * 4);
        grank += ((og > gs) || (og == gs && gg < g)) ? 1 : 0;
    }
    bool gsel = grank < 4;
    float candv = gsel ? swb : 0.0f;
    int erank = 0;
#pragma unroll
    for (int ee = 0; ee < 32; ee++) {
        float oc = __shfl(candv, ee);
        erank += ((oc > candv) || (oc == candv && ee < e)) ? 1 : 0;
    }
    bool esel = (erank < 8) && (half == 0);   // exactly 8 lanes (total order)
    unsigned long long m = __ballot(esel);
    int idx = __popcll(m & ((1ull << l) - 1ull));
    if (esel) topk[t * 8 + idx] = e;
    float r = esel ? sg : 0.f;
#pragma unroll
    for (int off = 1; off < 64; off <<= 1) r += __shfl_xor(r, off);
    float inv = SCALE_F / (r + 1e-20f);
    if (half == 0) combine[t * E_NUM + e] = esel ? sg * inv : 0.0f;
}

// ================= per-wave barrier-free 32x64 transpose-convert =================
// Each wave owns a private [16][68] float LDS buffer (4.25 KB). Two 16-row
// passes; LDS ops within a wave execute in order -> no barriers needed.
// Reads: bank = (4r + lane) % 32 -> 2-way (free). Store: 64 B contiguous/lane.
__device__ __forceinline__ void tcvt_wave(const float* __restrict__ src,
                                          unsigned short* __restrict__ dst,
                                          int C, int DS, int r0, int c0,
                                          float* wt) {
    int l = threadIdx.x & 63;
    int lr = l >> 2, c4 = l & 3;
    uint32_t up[2][8];
#pragma unroll
    for (int pass = 0; pass < 2; pass++) {
        const float* s0 = src + (size_t)(r0 + pass * 16 + lr) * C + c0 + c4 * 4;
        float4 v[4];
#pragma unroll
        for (int p = 0; p < 4; p++)
            v[p] = *reinterpret_cast<const float4*>(s0 + p * 16);
#pragma unroll
        for (int p = 0; p < 4; p++)
            *reinterpret_cast<float4*>(&wt[lr * 68 + c4 * 4 + p * 16]) = v[p];
        float w[16];
#pragma unroll
        for (int r = 0; r < 16; r++) w[r] = wt[r * 68 + l];
#pragma unroll
        for (int j = 0; j < 8; j++)
            up[pass][j] = (uint32_t)f2b(w[2 * j]) | ((uint32_t)f2b(w[2 * j + 1]) << 16);
    }
    unsigned short* dp = dst + (size_t)(c0 + l) * DS + r0;
    uint4 u;
    u.x = up[0][0]; u.y = up[0][1]; u.z = up[0][2]; u.w = up[0][3];
    *reinterpret_cast<uint4*>(dp) = u;
    u.x = up[0][4]; u.y = up[0][5]; u.z = up[0][6]; u.w = up[0][7];
    *reinterpret_cast<uint4*>(dp + 8) = u;
    u.x = up[1][0]; u.y = up[1][1]; u.z = up[1][2]; u.w = up[1][3];
    *reinterpret_cast<uint4*>(dp + 16) = u;
    u.x = up[1][4]; u.y = up[1][5]; u.z = up[1][6]; u.w = up[1][7];
    *reinterpret_cast<uint4*>(dp + 24) = u;
}

// ================= prep1: routing + x-cvt + BG/BU/SG/SU =================
// blocks [0,256): routing (4 tok/blk) | [256,512): cvt_x |
// [512,2048): transpose tiles (6144 waves x 3 tiles = 18432 tiles)
__global__ __launch_bounds__(256)
void prep1_kernel(const float* __restrict__ x, const float* __restrict__ gate_w,
                  const float* __restrict__ e_bias,
                  const float* __restrict__ w_gate, const float* __restrict__ w_up,
                  const float* __restrict__ ws_gate, const float* __restrict__ ws_up,
                  unsigned short* __restrict__ xb, float* __restrict__ combine,
                  int* __restrict__ topk,
                  unsigned short* __restrict__ BG, unsigned short* __restrict__ BU,
                  unsigned short* __restrict__ SG, unsigned short* __restrict__ SU) {
    __shared__ __align__(16) float tbuf[4][1088];
    int b = blockIdx.x;
    if (b < 256) {
        int t = b * 4 + (threadIdx.x >> 6);
        routing_wave(x, gate_w, e_bias, combine, topk, t);
        return;
    }
    if (b < 512) {
        int bb = b - 256;
#pragma unroll
        for (int p = 0; p < 4; p++) {
            int i = bb * 1024 + p * 256 + threadIdx.x;
            float4 v = reinterpret_cast<const float4*>(x)[i];
            uint2 o;
            o.x = (uint32_t)f2b(v.x) | ((uint32_t)f2b(v.y) << 16);
            o.y = (uint32_t)f2b(v.z) | ((uint32_t)f2b(v.w) << 16);
            reinterpret_cast<uint2*>(xb)[i] = o;
        }
        return;
    }
    int wid = (b - 512) * 4 + (threadIdx.x >> 6);
    float* wt = tbuf[threadIdx.x >> 6];
#pragma unroll 1
    for (int s = 0; s < 3; s++) {
        int t = wid * 3 + s;
        const float* src; unsigned short* dst; int C, tr, tc;
        if (t < 8192) {
            int e = t >> 8, rem = t & 255;
            src = w_gate + (size_t)e * 524288; dst = BG + (size_t)e * 524288;
            C = 512; tr = rem & 31; tc = rem >> 5;
        } else if (t < 16384) {
            int tt = t - 8192; int e = tt >> 8, rem = tt & 255;
            src = w_up + (size_t)e * 524288; dst = BU + (size_t)e * 524288;
            C = 512; tr = rem & 31; tc = rem >> 5;
        } else if (t < 17408) {
            int rem = t - 16384;
            src = ws_gate; dst = SG; C = 2048; tr = rem & 31; tc = rem >> 5;
        } else {
            int rem = t - 17408;
            src = ws_up; dst = SU; C = 2048; tr = rem & 31; tc = rem >> 5;
        }
        tcvt_wave(src, dst, C, 1024, tr * 32, tc * 64, wt);
    }
}

// ---------------- build expert segments (single block, 1024 threads) ----------------
__global__ __launch_bounds__(1024)
void listbuild_kernel(const int* __restrict__ topk, int* __restrict__ meta,
                      int* __restrict__ pair_token, int* __restrict__ slot_of) {
    __shared__ int cnt[E_NUM], start[E_NUM], fill[E_NUM];
    int t = threadIdx.x;
    if (t < E_NUM) cnt[t] = 0;
    __syncthreads();
    int ids[8];
#pragma unroll
    for (int r = 0; r < 8; r++) {
        ids[r] = topk[t * 8 + r];
        atomicAdd(&cnt[ids[r]], 1);
    }
    __syncthreads();
    if (t == 0) {
        int acc = 0;
        for (int e = 0; e < E_NUM; e++) {
            int nt = (cnt[e] + 127) >> 7;
            start[e] = acc * 128;
            fill[e] = 0;
            for (int j = 0; j < nt; j++) meta[1 + acc + j] = e;
            acc += nt;
        }
        meta[0] = acc;
    }
    __syncthreads();
    for (int i = t; i < MAXTILES * 128; i += 1024) pair_token[i] = 0;
    __syncthreads();
#pragma unroll
    for (int r = 0; r < 8; r++) {
        int e = ids[r];
        int s = start[e] + atomicAdd(&fill[e], 1);
        pair_token[s] = t;
        slot_of[t * 8 + r] = s;
    }
}

// ================= fused gate/up + BDs/BSD converts =================
// blocks [0,384): routed gateup | [384,512): shared gateup |
// [512,1280): per-wave converts (3072 waves x 3 tiles = 9216 tiles)
__global__ __launch_bounds__(256, 2)
void gateup_fused(const unsigned short* __restrict__ xb,
                  const unsigned short* __restrict__ BG,
                  const unsigned short* __restrict__ BU,
                  const unsigned short* __restrict__ SG,
                  const unsigned short* __restrict__ SU,
                  const float* __restrict__ combine,
                  const int* __restrict__ pair_token,
                  const int* __restrict__ meta,
                  const float* __restrict__ w_down,
                  const float* __restrict__ ws_down,
                  unsigned short* __restrict__ BDs,
                  unsigned short* __restrict__ BSD,
                  unsigned short* __restrict__ act_s,
                  unsigned short* __restrict__ act_sh) {
    __shared__ __align__(16) unsigned short smem[24576];   // 48 KB, overlaid
    int b = blockIdx.x;
    if (b >= 512) {
        // -------- per-wave convert path (overlaps with GEMM blocks) --------
        float* wt = reinterpret_cast<float*>(smem) + (threadIdx.x >> 6) * 1088;
        int wid = (b - 512) * 4 + (threadIdx.x >> 6);
#pragma unroll 1
        for (int s = 0; s < 3; s++) {
            int t = wid * 3 + s;
            const float* src; unsigned short* dst; int C, DS, tr, tc;
            if (t < 8192) {
                int e = t >> 8, rem = t & 255;
                src = w_down + (size_t)e * 524288; dst = BDs + (size_t)e * 524288;
                C = 1024; DS = 512; tr = rem & 15; tc = rem >> 4;
            } else {
                int rem = t - 8192;
                src = ws_down; dst = BSD; C = 1024; DS = 2048; tr = rem & 63; tc = rem >> 6;
            }
            tcvt_wave(src, dst, C, DS, tr * 32, tc * 64, wt);
        }
        return;
    }
    bool routed = b < 384;
    int tid = threadIdx.x, lane = tid & 63, w = tid >> 6;
    int wr = w >> 1, wc = w & 1;
    unsigned short* lA  = smem;           // [2][4096]
    unsigned short* lBg = smem + 8192;    // [2][4096]
    unsigned short* lBu = smem + 16384;   // [2][4096]

    int srow = w * 32 + (lane >> 2);
    int schunk = (lane & 3) * 8;
    int aoff = (w * 32) * 32;

    const unsigned short *gA0, *gA1, *gG0, *gU0;
    int e = 0, slot0 = 0, row0 = 0, ci0 = 0;
    if (routed) {
        int tile = b >> 2;
        if (tile >= meta[0]) return;
        e = meta[1 + tile];
        ci0 = (b & 3) * 128;
        slot0 = tile * 128;
        int brow0 = e * I_DIM + ci0;
        int tok0 = pair_token[slot0 + srow];
        int tok1 = pair_token[slot0 + srow + 16];
        gA0 = xb + (size_t)tok0 * H_DIM + schunk;
        gA1 = xb + (size_t)tok1 * H_DIM + schunk;
        gG0 = BG + (size_t)(brow0 + srow) * H_DIM + schunk;
        gU0 = BU + (size_t)(brow0 + srow) * H_DIM + schunk;
    } else {
        int bb = b - 384;
        row0 = (bb >> 4) * 128;
        ci0 = (bb & 15) * 128;
        gA0 = xb + (size_t)(row0 + srow) * H_DIM + schunk;
        gA1 = gA0 + 16 * H_DIM;
        gG0 = SG + (size_t)(ci0 + srow) * H_DIM + schunk;
        gU0 = SU + (size_t)(ci0 + srow) * H_DIM + schunk;
    }

    f32x4 accg[4][4], accu[4][4];
#pragma unroll
    for (int i = 0; i < 4; i++)
#pragma unroll
        for (int j = 0; j < 4; j++)
#pragma unroll
            for (int r = 0; r < 4; r++) { accg[i][j][r] = 0.f; accu[i][j][r] = 0.f; }

#define GU_STAGE(KK, BSEL)                                        \
    do {                                                          \
        int _k0 = (KK) * 32;                                      \
        unsigned short* _a = lA + (BSEL) * 4096 + aoff;           \
        gll16(gA0 + _k0, _a);                                     \
        gll16(gA1 + _k0, _a + 16 * 32);                           \
        unsigned short* _g = lBg + (BSEL) * 4096 + aoff;          \
        gll16(gG0 + _k0, _g);                                     \
        gll16(gG0 + 16 * H_DIM + _k0, _g + 16 * 32);              \
        unsigned short* _u = lBu + (BSEL) * 4096 + aoff;          \
        gll16(gU0 + _k0, _u);                                     \
        gll16(gU0 + 16 * H_DIM + _k0, _u + 16 * 32);              \
    } while (0)

    GU_STAGE(0, 0);
    __syncthreads();   // vmcnt(0) drain + barrier: buf0 ready
    for (int kk = 0; kk < 32; kk++) {
        int cur = kk & 1;
        if (kk < 31) GU_STAGE(kk + 1, cur ^ 1);     // prefetch next tile
        bf16x8 af[4], bgf[4], buf2[4];
#pragma unroll
        for (int mi = 0; mi < 4; mi++)
            af[mi] = *reinterpret_cast<const bf16x8*>(
                &lA[cur * 4096 + (wr * 64 + mi * 16 + (lane & 15)) * 32 + (lane >> 4) * 8]);
#pragma unroll
        for (int ni = 0; ni < 4; ni++) {
            int nn = cur * 4096 + (wc * 64 + ni * 16 + (lane & 15)) * 32 + (lane >> 4) * 8;
            bgf[ni] = *reinterpret_cast<const bf16x8*>(&lBg[nn]);
            buf2[ni] = *reinterpret_cast<const bf16x8*>(&lBu[nn]);
        }
#pragma unroll
        for (int mi = 0; mi < 4; mi++)
#pragma unroll
            for (int ni = 0; ni < 4; ni++) {
                accg[mi][ni] = __builtin_amdgcn_mfma_f32_16x16x32_bf16(af[mi], bgf[ni], accg[mi][ni], 0, 0, 0);
                accu[mi][ni] = __builtin_amdgcn_mfma_f32_16x16x32_bf16(af[mi], buf2[ni], accu[mi][ni], 0, 0, 0);
            }
        __syncthreads();   // drains next-tile stage (vmcnt 0) + barrier
    }
#undef GU_STAGE

    int q = lane >> 4, cl = lane & 15;
    if (routed) {
#pragma unroll
        for (int mi = 0; mi < 4; mi++) {
#pragma unroll
            for (int r = 0; r < 4; r++) {
                int row = wr * 64 + mi * 16 + q * 4 + r;
                int token = pair_token[slot0 + row];
                float s = combine[token * E_NUM + e];
#pragma unroll
                for (int ni = 0; ni < 4; ni++) {
                    float g = accg[mi][ni][r], u = accu[mi][ni][r];
                    float a = g / (1.f + expf(-g)) * u * s;
                    act_s[(size_t)(slot0 + row) * I_DIM + ci0 + wc * 64 + ni * 16 + cl] = f2b(a);
                }
            }
        }
    } else {
#pragma unroll
        for (int mi = 0; mi < 4; mi++) {
#pragma unroll
            for (int ni = 0; ni < 4; ni++) {
                int col = ci0 + wc * 64 + ni * 16 + cl;
#pragma unroll
                for (int r = 0; r < 4; r++) {
                    int row = row0 + wr * 64 + mi * 16 + q * 4 + r;
                    float g = accg[mi][ni][r], u = accu[mi][ni][r];
                    float a = g / (1.f + expf(-g)) * u;
                    act_sh[(size_t)row * IS_DIM + col] = f2b(a);
                }
            }
        }
    }
}

// ================= fused down: routed (blocks 0..767) + shared splitK (768..1023) =================
__global__ __launch_bounds__(256, 2)
void down_fused(const unsigned short* __restrict__ act_s,
                const unsigned short* __restrict__ BDs,
                const unsigned short* __restrict__ act_sh,
                const unsigned short* __restrict__ BSD,
                const int* __restrict__ meta,
                float* __restrict__ pairpart,
                float* __restrict__ shpart) {
    int b = blockIdx.x;
    bool routed = b < 768;
    int tid = threadIdx.x, lane = tid & 63, w = tid >> 6;
    int wr = w >> 1, wc = w & 1;
    __shared__ __align__(16) unsigned short lA[2][128 * 32];
    __shared__ __align__(16) unsigned short lB[2][128 * 32];

    int srow = w * 32 + (lane >> 2);
    int schunk = (lane & 3) * 8;
    int aoff = (w * 32) * 32;

    const unsigned short *gA0, *gB0;
    size_t ast, bst;
    int kbase, n0, orow;
    float* outp;
    if (routed) {
        int tile = b >> 3;
        if (tile >= meta[0]) return;
        int e = meta[1 + tile];
        n0 = (b & 7) * 128;
        int slot0 = tile * 128;
        gA0 = act_s + (size_t)(slot0 + srow) * I_DIM + schunk;
        gB0 = BDs + (size_t)e * H_DIM * I_DIM + (size_t)(n0 + srow) * I_DIM + schunk;
        ast = I_DIM; bst = I_DIM; kbase = 0;
        outp = pairpart; orow = slot0;
    } else {
        int bb = b - 768;
        int mb = bb >> 5, nb = (bb >> 2) & 7, ks = bb & 3;
        int row0 = mb * 128;
        n0 = nb * 128;
        gA0 = act_sh + (size_t)(row0 + srow) * IS_DIM + schunk;
        gB0 = BSD + (size_t)(n0 + srow) * IS_DIM + schunk;
        ast = IS_DIM; bst = IS_DIM; kbase = ks * 512;
        outp = shpart + ((size_t)ks << 20); orow = row0;
    }

    f32x4 acc[4][4];
#pragma unroll
    for (int i = 0; i < 4; i++)
#pragma unroll
        for (int j = 0; j < 4; j++)
#pragma unroll
            for (int r = 0; r < 4; r++) acc[i][j][r] = 0.f;

#define DN_STAGE(KK, BSEL)                                        \
    do {                                                          \
        size_t _k0 = (size_t)kbase + (size_t)(KK) * 32;           \
        unsigned short* _a = &lA[BSEL][aoff];                     \
        gll16(gA0 + _k0, _a);                                     \
        gll16(gA0 + 16 * ast + _k0, _a + 16 * 32);                \
        unsigned short* _b2 = &lB[BSEL][aoff];                    \
        gll16(gB0 + _k0, _b2);                                    \
        gll16(gB0 + 16 * bst + _k0, _b2 + 16 * 32);               \
    } while (0)

    DN_STAGE(0, 0);
    __syncthreads();
    for (int kk = 0; kk < 16; kk++) {
        int cur = kk & 1;
        if (kk < 15) DN_STAGE(kk + 1, cur ^ 1);
        bf16x8 af[4], bf[4];
#pragma unroll
        for (int mi = 0; mi < 4; mi++)
            af[mi] = *reinterpret_cast<const bf16x8*>(
                &lA[cur][(wr * 64 + mi * 16 + (lane & 15)) * 32 + (lane >> 4) * 8]);
#pragma unroll
        for (int ni = 0; ni < 4; ni++)
            bf[ni] = *reinterpret_cast<const bf16x8*>(
                &lB[cur][(wc * 64 + ni * 16 + (lane & 15)) * 32 + (lane >> 4) * 8]);
#pragma unroll
        for (int mi = 0; mi < 4; mi++)
#pragma unroll
            for (int ni = 0; ni < 4; ni++)
                acc[mi][ni] = __builtin_amdgcn_mfma_f32_16x16x32_bf16(af[mi], bf[ni], acc[mi][ni], 0, 0, 0);
        __syncthreads();
    }
#undef DN_STAGE

    int q = lane >> 4, cl = lane & 15;
#pragma unroll
    for (int mi = 0; mi < 4; mi++) {
#pragma unroll
        for (int ni = 0; ni < 4; ni++) {
            int col = n0 + wc * 64 + ni * 16 + cl;
#pragma unroll
            for (int r = 0; r < 4; r++) {
                int row = orow + wr * 64 + mi * 16 + q * 4 + r;
                outp[(size_t)row * H_DIM + col] = acc[mi][ni][r];
            }
        }
    }
}

// ---------------- final combine ----------------
__global__ void final_combine(const float* __restrict__ pairpart,
                              const float* __restrict__ shpart,
                              const int* __restrict__ slot_of,
                              float* __restrict__ out) {
    int t = blockIdx.x;
    int h = threadIdx.x * 4;
    float4 o = reinterpret_cast<const float4*>(shpart + (size_t)t * H_DIM + h)[0];
#pragma unroll
    for (int ks = 1; ks < 4; ks++) {
        float4 v = reinterpret_cast<const float4*>(shpart + ((size_t)ks << 20) + (size_t)t * H_DIM + h)[0];
        o.x += v.x; o.y += v.y; o.z += v.z; o.w += v.w;
    }
#pragma unroll
    for (int r = 0; r < 8; r++) {
        int s = slot_of[t * 8 + r];
        float4 v = reinterpret_cast<const float4*>(pairpart + (size_t)s * H_DIM + h)[0];
        o.x += v.x; o.y += v.y; o.z += v.z; o.w += v.w;
    }
    reinterpret_cast<float4*>(out + (size_t)t * H_DIM + h)[0] = o;
}

// ================= FALLBACK PATH (round-1 kernels, small ws) =================

__global__ void cvt_x_kernel(const float* __restrict__ x, unsigned short* __restrict__ xb) {
    int i = blockIdx.x * 256 + threadIdx.x;
    float4 v = reinterpret_cast<const float4*>(x)[i];
    uint2 o;
    o.x = (uint32_t)f2b(v.x) | ((uint32_t)f2b(v.y) << 16);
    o.y = (uint32_t)f2b(v.z) | ((uint32_t)f2b(v.w) << 16);
    reinterpret_cast<uint2*>(xb)[i] = o;
}

__global__ void routing_kernel(const float* __restrict__ x,
                               const float* __restrict__ gate_w,
                               const float* __restrict__ e_bias,
                               float* __restrict__ combine,
                               int* __restrict__ topk) {
    int t = blockIdx.x;
    routing_wave(x, gate_w, e_bias, combine, topk, t);
}

__global__ __launch_bounds__(256, 2)
void gateup_kernel(const unsigned short* __restrict__ xb,
                   const float* __restrict__ w_gate,
                   const float* __restrict__ w_up,
                   const float* __restrict__ ws_gate,
                   const float* __restrict__ ws_up,
                   const float* __restrict__ combine,
                   unsigned short* __restrict__ act) {
    int mb = blockIdx.x, cb = blockIdx.y;
    int row0 = mb * 128, c0 = cb * 128;
    const float *bg, *bu;
    int bstride, eidx;
    if (c0 < NCOL_R) {
        int e = c0 >> 9, ci = c0 & 511;
        bg = w_gate + (size_t)e * H_DIM * I_DIM + ci;
        bu = w_up   + (size_t)e * H_DIM * I_DIM + ci;
        bstride = I_DIM; eidx = e;
    } else {
        int ci = c0 - NCOL_R;
        bg = ws_gate + ci; bu = ws_up + ci;
        bstride = IS_DIM; eidx = -1;
    }
    __shared__ __align__(16) unsigned short lA[128*32];
    __shared__ __align__(16) unsigned short lBg[128*32];
    __shared__ __align__(16) unsigned short lBu[128*32];
    int tid = threadIdx.x, lane = tid & 63, w = tid >> 6;
    int wr = w >> 1, wc = w & 1;
    f32x4 accg[4][4], accu[4][4];
#pragma unroll
    for (int i = 0; i < 4; i++)
#pragma unroll
        for (int j = 0; j < 4; j++)
#pragma unroll
            for (int r = 0; r < 4; r++) { accg[i][j][r] = 0.f; accu[i][j][r] = 0.f; }
    int ar = tid >> 2, ak = (tid & 3) * 8;
    int bn = tid & 127, bkg = (tid >> 7) * 16;
    for (int kk = 0; kk < H_DIM / 32; kk++) {
        int k0 = kk * 32;
        __syncthreads();
        *reinterpret_cast<uint4*>(&lA[ar*32 + ak]) =
            *reinterpret_cast<const uint4*>(xb + (size_t)(row0 + ar) * H_DIM + k0 + ak);
        *reinterpret_cast<uint4*>(&lA[(ar+64)*32 + ak]) =
            *reinterpret_cast<const uint4*>(xb + (size_t)(row0 + ar + 64) * H_DIM + k0 + ak);
#pragma unroll
        for (int p = 0; p < 4; p++) {
            int kb = bkg + p * 4;
            const float* pg = bg + (size_t)(k0 + kb) * bstride + bn;
            uint2 dg;
            dg.x = (uint32_t)f2b(pg[0])         | ((uint32_t)f2b(pg[bstride])   << 16);
            dg.y = (uint32_t)f2b(pg[2*bstride]) | ((uint32_t)f2b(pg[3*bstride]) << 16);
            *reinterpret_cast<uint2*>(&lBg[bn*32 + kb]) = dg;
            const float* pu = bu + (size_t)(k0 + kb) * bstride + bn;
            uint2 du;
            du.x = (uint32_t)f2b(pu[0])         | ((uint32_t)f2b(pu[bstride])   << 16);
            du.y = (uint32_t)f2b(pu[2*bstride]) | ((uint32_t)f2b(pu[3*bstride]) << 16);
            *reinterpret_cast<uint2*>(&lBu[bn*32 + kb]) = du;
        }
        __syncthreads();
        bf16x8 af[4], bgf[4], buf2[4];
#pragma unroll
        for (int mi = 0; mi < 4; mi++)
            af[mi] = *reinterpret_cast<const bf16x8*>(&lA[(wr*64 + mi*16 + (lane & 15))*32 + (lane >> 4)*8]);
#pragma unroll
        for (int ni = 0; ni < 4; ni++) {
            int nn = (wc*64 + ni*16 + (lane & 15))*32 + (lane >> 4)*8;
            bgf[ni]  = *reinterpret_cast<const bf16x8*>(&lBg[nn]);
            buf2[ni] = *reinterpret_cast<const bf16x8*>(&lBu[nn]);
        }
#pragma unroll
        for (int mi = 0; mi < 4; mi++)
#pragma unroll
            for (int ni = 0; ni < 4; ni++) {
                accg[mi][ni] = __builtin_amdgcn_mfma_f32_16x16x32_bf16(af[mi], bgf[ni],  accg[mi][ni], 0, 0, 0);
                accu[mi][ni] = __builtin_amdgcn_mfma_f32_16x16x32_bf16(af[mi], buf2[ni], accu[mi][ni], 0, 0, 0);
            }
    }
    int q = lane >> 4, cl = lane & 15;
#pragma unroll
    for (int mi = 0; mi < 4; mi++) {
#pragma unroll
        for (int ni = 0; ni < 4; ni++) {
            int colg = c0 + wc*64 + ni*16 + cl;
#pragma unroll
            for (int r = 0; r < 4; r++) {
                int row = row0 + wr*64 + mi*16 + q*4 + r;
                float g = accg[mi][ni][r], u = accu[mi][ni][r];
                float a = g / (1.f + expf(-g)) * u;
                float s = (eidx >= 0) ? combine[row * E_NUM + eidx] : 1.0f;
                act[(size_t)row * NCOL_T + colg] = f2b(a * s);
            }
        }
    }
}

__global__ __launch_bounds__(256, 2)
void down_kernel(const unsigned short* __restrict__ act,
                 const float* __restrict__ w_down,
                 const float* __restrict__ ws_down,
                 float* __restrict__ partials) {
    int mb = blockIdx.x, nb = blockIdx.y, ks = blockIdx.z;
    int row0 = mb * 128, n0 = nb * 128;
    __shared__ __align__(16) unsigned short lA[128*32];
    __shared__ __align__(16) unsigned short lB[128*32];
    int tid = threadIdx.x, lane = tid & 63, w = tid >> 6;
    int wr = w >> 1, wc = w & 1;
    f32x4 acc[4][4];
#pragma unroll
    for (int i = 0; i < 4; i++)
#pragma unroll
        for (int j = 0; j < 4; j++)
#pragma unroll
            for (int r = 0; r < 4; r++) acc[i][j][r] = 0.f;
    int ar = tid >> 2, ak = (tid & 3) * 8;
    int bn = tid & 127, bkg = (tid >> 7) * 16;
    for (int kk = 0; kk < 144; kk++) {
        int k0 = ks * 4608 + kk * 32;
        const float* bb = (k0 < NCOL_R) ? (w_down + (size_t)k0 * H_DIM)
                                        : (ws_down + (size_t)(k0 - NCOL_R) * H_DIM);
        __syncthreads();
        *reinterpret_cast<uint4*>(&lA[ar*32 + ak]) =
            *reinterpret_cast<const uint4*>(act + (size_t)(row0 + ar) * NCOL_T + k0 + ak);
        *reinterpret_cast<uint4*>(&lA[(ar+64)*32 + ak]) =
            *reinterpret_cast<const uint4*>(act + (size_t)(row0 + ar + 64) * NCOL_T + k0 + ak);
#pragma unroll
        for (int p = 0; p < 4; p++) {
            int kb = bkg + p * 4;
            const float* pb = bb + (size_t)kb * H_DIM + n0 + bn;
            uint2 d;
            d.x = (uint32_t)f2b(pb[0])       | ((uint32_t)f2b(pb[H_DIM])   << 16);
            d.y = (uint32_t)f2b(pb[2*H_DIM]) | ((uint32_t)f2b(pb[3*H_DIM]) << 16);
            *reinterpret_cast<uint2*>(&lB[bn*32 + kb]) = d;
        }
        __syncthreads();
        bf16x8 af[4], bf[4];
#pragma unroll
        for (int mi = 0; mi < 4; mi++)
            af[mi] = *reinterpret_cast<const bf16x8*>(&lA[(wr*64 + mi*16 + (lane & 15))*32 + (lane >> 4)*8]);
#pragma unroll
        for (int ni = 0; ni < 4; ni++)
            bf[ni] = *reinterpret_cast<const bf16x8*>(&lB[(wc*64 + ni*16 + (lane & 15))*32 + (lane >> 4)*8]);
#pragma unroll
        for (int mi = 0; mi < 4; mi++)
#pragma unroll
            for (int ni = 0; ni < 4; ni++)
                acc[mi][ni] = __builtin_amdgcn_mfma_f32_16x16x32_bf16(af[mi], bf[ni], acc[mi][ni], 0, 0, 0);
    }
    float* pout = partials + ((size_t)ks << 20);
    int q = lane >> 4, cl = lane & 15;
#pragma unroll
    for (int mi = 0; mi < 4; mi++) {
#pragma unroll
        for (int ni = 0; ni < 4; ni++) {
            int col = n0 + wc*64 + ni*16 + cl;
#pragma unroll
            for (int r = 0; r < 4; r++) {
                int row = row0 + wr*64 + mi*16 + q*4 + r;
                pout[(size_t)row * H_DIM + col] = acc[mi][ni][r];
            }
        }
    }
}

__global__ void reduce_kernel(const float* __restrict__ p, float* __restrict__ out) {
    int i = blockIdx.x * 256 + threadIdx.x;
    float4 a = reinterpret_cast<const float4*>(p)[i];
    float4 b = reinterpret_cast<const float4*>(p + (size_t)1048576)[i];
    float4 c = reinterpret_cast<const float4*>(p + (size_t)2097152)[i];
    float4 d = reinterpret_cast<const float4*>(p + (size_t)3145728)[i];
    float4 o;
    o.x = a.x + b.x + c.x + d.x;
    o.y = a.y + b.y + c.y + d.y;
    o.z = a.z + b.z + c.z + d.z;
    o.w = a.w + b.w + c.w + d.w;
    reinterpret_cast<float4*>(out)[i] = o;
}

extern "C" void kernel_launch(void* const* d_in, const int* in_sizes, int n_in,
                              void* d_out, int out_size, void* d_ws, size_t ws_size,
                              hipStream_t stream) {
    const float* x       = (const float*)d_in[0];
    const float* gate_w  = (const float*)d_in[1];
    const float* e_bias  = (const float*)d_in[2];
    const float* w_gate  = (const float*)d_in[3];
    const float* w_up    = (const float*)d_in[4];
    const float* w_down  = (const float*)d_in[5];
    const float* ws_gate = (const float*)d_in[6];
    const float* ws_up   = (const float*)d_in[7];
    const float* ws_down = (const float*)d_in[8];
    float* out = (float*)d_out;

    char* ws = (char*)d_ws;
    bool fast = ws_size >= 170000384ull;   // ws_size constant across calls -> capture-safe branch

    if (fast) {
        float* combine      = (float*)(ws);                       // 131072
        int*   topk         = (int*)(ws + 131072);                // 32768
        int*   meta         = (int*)(ws + 163840);                // 512
        int*   pair_token   = (int*)(ws + 164352);                // 49152
        int*   slot_of      = (int*)(ws + 213504);                // 32768
        unsigned short* xb  = (unsigned short*)(ws + 262144);     // 2 MB
        unsigned short* act_s  = (unsigned short*)(ws + 2359296);    // 12.6 MB
        unsigned short* act_sh = (unsigned short*)(ws + 14942208);   // 4 MB
        unsigned short* BG  = (unsigned short*)(ws + 19136512);      // 32 MB
        unsigned short* BU  = (unsigned short*)(ws + 52690944);      // 32 MB
        unsigned short* SG  = (unsigned short*)(ws + 86245376);      // 4 MB
        unsigned short* SU  = (unsigned short*)(ws + 90439680);      // 4 MB
        unsigned short* BDs = (unsigned short*)(ws + 94633984);      // 32 MB
        unsigned short* BSD = (unsigned short*)(ws + 128188416);     // 4 MB
        // partials alias dead BG/BU region (BG/BU only used by gateup_fused)
        float* pairpart     = (float*)(ws + 19136512);               // 50.33 MB
        float* shpart       = (float*)(ws + 69468160);               // 16 MB, ends 86245376

        prep1_kernel<<<2048, 256, 0, stream>>>(x, gate_w, e_bias, w_gate, w_up,
                                               ws_gate, ws_up,
                                               xb, combine, topk, BG, BU, SG, SU);
        listbuild_kernel<<<1, 1024, 0, stream>>>(topk, meta, pair_token, slot_of);
        gateup_fused<<<1280, 256, 0, stream>>>(xb, BG, BU, SG, SU, combine, pair_token, meta,
                                               w_down, ws_down, BDs, BSD, act_s, act_sh);
        down_fused<<<1024, 256, 0, stream>>>(act_s, BDs, act_sh, BSD, meta, pairpart, shpart);
        final_combine<<<1024, 256, 0, stream>>>(pairpart, shpart, slot_of, out);
    } else {
        float* combine     = (float*)(ws);
        int*   topk        = (int*)(ws + 131072);
        unsigned short* xb = (unsigned short*)(ws + 262144);
        unsigned short* act= (unsigned short*)(ws + 2359296);
        float* partials    = (float*)(ws + 40108032);

        cvt_x_kernel<<<1024, 256, 0, stream>>>(x, xb);
        routing_kernel<<<1024, 64, 0, stream>>>(x, gate_w, e_bias, combine, topk);
        gateup_kernel<<<dim3(8, 144), 256, 0, stream>>>(xb, w_gate, w_up, ws_gate, ws_up, combine, act);
        down_kernel<<<dim3(8, 8, 4), 256, 0, stream>>>(act, w_down, ws_down, partials);
        reduce_kernel<<<1024, 256, 0, stream>>>(partials, out);
    }
}

// Round 5
// 337.776 us; speedup vs baseline: 1.1000x; 1.1000x over previous
//
#include <hip/hip_runtime.h>
#include <cstdint>
#include <cmath>

#define T_TOK 1024
#define H_DIM 1024
#define E_NUM 32
#define I_DIM 512
#define IS_DIM 2048
#define NCOL_R 16384
#define NCOL_T 18432
#define SCALE_F 2.5f
#define MAXTILES 96

typedef __bf16 bf16x8 __attribute__((ext_vector_type(8)));
typedef float f32x4 __attribute__((ext_vector_type(4)));

typedef __attribute__((address_space(3))) unsigned int lds_u32_t;
typedef __attribute__((address_space(1))) const unsigned int glb_u32_t;

__device__ __forceinline__ unsigned short f2b(float f) {
    union { float f; uint32_t u; } v; v.f = f;
    return (unsigned short)((v.u + 0x7FFFu + ((v.u >> 16) & 1u)) >> 16);
}

// 2x fp32 -> packed 2x bf16, RNE (identical rounding to f2b). gfx950 HW op.
__device__ __forceinline__ uint32_t cvt2(float lo, float hi) {
    uint32_t r;
    asm("v_cvt_pk_bf16_f32 %0, %1, %2" : "=v"(r) : "v"(lo), "v"(hi));
    return r;
}

__device__ __forceinline__ void gll16(const unsigned short* g, unsigned short* l) {
    __builtin_amdgcn_global_load_lds((glb_u32_t*)g, (lds_u32_t*)l, 16, 0, 0);
}

// ================= lane-parallel routing: one wave per token =================
__device__ __forceinline__ void routing_wave(const float* __restrict__ x,
                                             const float* __restrict__ gate_w,
                                             const float* __restrict__ e_bias,
                                             float* __restrict__ combine,
                                             int* __restrict__ topk, int t) {
    int l = threadIdx.x & 63;
    int e = l & 31, half = l >> 5;
    const float4* xr = reinterpret_cast<const float4*>(x + (size_t)t * H_DIM + half * 512);
    const float4* wr = reinterpret_cast<const float4*>(gate_w + (size_t)e * H_DIM + half * 512);
    float s = 0.f;
#pragma unroll 8
    for (int j = 0; j < 128; j++) {
        float4 a = xr[j], b = wr[j];
        s += a.x * b.x + a.y * b.y + a.z * b.z + a.w * b.w;
    }
    s += __shfl_xor(s, 32);            // lanes 0..31 (dup in 32..63) hold logit[e]
    float sg = 1.f / (1.f + expf(-s));
    float swb = sg + e_bias[e];
    // group top-2 sum (group = 4 consecutive experts; pairing-invariant formula)
    float v1 = __shfl_xor(swb, 1), v2 = __shfl_xor(swb, 2), v3 = __shfl_xor(swb, 3);
    float hi01 = fmaxf(swb, v1), lo01 = fminf(swb, v1);
    float hi23 = fmaxf(v2, v3),  lo23 = fminf(v2, v3);
    float gs = fmaxf(hi01, hi23) + fmaxf(fminf(hi01, hi23), fmaxf(lo01, lo23));
    int g = e >> 2;
    int grank = 0;
#pragma unroll
    for (int gg = 0; gg < 8; gg++) {
        float og = __shfl(gs, gg * 4);
        grank += ((og > gs) || (og == gs && gg < g)) ? 1 : 0;
    }
    bool gsel = grank < 4;
    float candv = gsel ? swb : 0.0f;
    int erank = 0;
#pragma unroll
    for (int ee = 0; ee < 32; ee++) {
        float oc = __shfl(candv, ee);
        erank += ((oc > candv) || (oc == candv && ee < e)) ? 1 : 0;
    }
    bool esel = (erank < 8) && (half == 0);   // exactly 8 lanes (total order)
    unsigned long long m = __ballot(esel);
    int idx = __popcll(m & ((1ull << l) - 1ull));
    if (esel) topk[t * 8 + idx] = e;
    float r = esel ? sg : 0.f;
#pragma unroll
    for (int off = 1; off < 64; off <<= 1) r += __shfl_xor(r, off);
    float inv = SCALE_F / (r + 1e-20f);
    if (half == 0) combine[t * E_NUM + e] = esel ? sg * inv : 0.0f;
}

// ================= prep1: routing + x-cvt only (weights go direct-fp32) =================
// blocks [0,256): routing (4 tok/blk) | [256,512): cvt_x
__global__ __launch_bounds__(256)
void prep1_kernel(const float* __restrict__ x, const float* __restrict__ gate_w,
                  const float* __restrict__ e_bias,
                  unsigned short* __restrict__ xb, float* __restrict__ combine,
                  int* __restrict__ topk) {
    int b = blockIdx.x;
    if (b < 256) {
        int t = b * 4 + (threadIdx.x >> 6);
        routing_wave(x, gate_w, e_bias, combine, topk, t);
        return;
    }
    int bb = b - 256;
#pragma unroll
    for (int p = 0; p < 4; p++) {
        int i = bb * 1024 + p * 256 + threadIdx.x;
        float4 v = reinterpret_cast<const float4*>(x)[i];
        uint2 o;
        o.x = cvt2(v.x, v.y);
        o.y = cvt2(v.z, v.w);
        reinterpret_cast<uint2*>(xb)[i] = o;
    }
}

// ---------------- build expert segments (single block, 1024 threads) ----------------
__global__ __launch_bounds__(1024)
void listbuild_kernel(const int* __restrict__ topk, int* __restrict__ meta,
                      int* __restrict__ pair_token, int* __restrict__ slot_of) {
    __shared__ int cnt[E_NUM], start[E_NUM], fill[E_NUM];
    int t = threadIdx.x;
    if (t < E_NUM) cnt[t] = 0;
    __syncthreads();
    int ids[8];
#pragma unroll
    for (int r = 0; r < 8; r++) {
        ids[r] = topk[t * 8 + r];
        atomicAdd(&cnt[ids[r]], 1);
    }
    __syncthreads();
    if (t == 0) {
        int acc = 0;
        for (int e = 0; e < E_NUM; e++) {
            int nt = (cnt[e] + 127) >> 7;
            start[e] = acc * 128;
            fill[e] = 0;
            for (int j = 0; j < nt; j++) meta[1 + acc + j] = e;
            acc += nt;
        }
        meta[0] = acc;
    }
    __syncthreads();
    for (int i = t; i < MAXTILES * 128; i += 1024) pair_token[i] = 0;
    __syncthreads();
#pragma unroll
    for (int r = 0; r < 8; r++) {
        int e = ids[r];
        int s = start[e] + atomicAdd(&fill[e], 1);
        pair_token[s] = t;
        slot_of[t * 8 + r] = s;
    }
}

// ================= fused gate/up, direct-fp32 B =================
// blocks [0,384): routed | [384,512): shared.
// B staged: 16 strided fp32 loads/thread (coalesced across lanes) -> cvt_pk -> LDS.
// LDS B rows padded to 40 halfwords (80 B) to break write bank conflicts.
// Pipeline: issue loads(k+1) + gll A(k+1) -> MFMA(k) -> barrier -> cvt+write(k+1) -> barrier.
__global__ __launch_bounds__(256, 2)
void gateup_fused(const unsigned short* __restrict__ xb,
                  const float* __restrict__ w_gate,
                  const float* __restrict__ w_up,
                  const float* __restrict__ ws_gate,
                  const float* __restrict__ ws_up,
                  const float* __restrict__ combine,
                  const int* __restrict__ pair_token,
                  const int* __restrict__ meta,
                  unsigned short* __restrict__ act_s,
                  unsigned short* __restrict__ act_sh) {
    int b = blockIdx.x;
    bool routed = b < 384;
    int tid = threadIdx.x, lane = tid & 63, w = tid >> 6;
    int wr = w >> 1, wc = w & 1;
    __shared__ __align__(16) unsigned short lA[2][128 * 32];
    __shared__ __align__(16) unsigned short lBg[2][128 * 40];
    __shared__ __align__(16) unsigned short lBu[2][128 * 40];

    int srow = w * 32 + (lane >> 2);
    int schunk = (lane & 3) * 8;
    int aoff = (w * 32) * 32;

    const unsigned short *gA0, *gA1;
    const float *gBg, *gBu;
    int bstride;
    int e = 0, slot0 = 0, row0 = 0, ci0 = 0;
    if (routed) {
        int tile = b >> 2;
        if (tile >= meta[0]) return;
        e = meta[1 + tile];
        ci0 = (b & 3) * 128;
        slot0 = tile * 128;
        int tok0 = pair_token[slot0 + srow];
        int tok1 = pair_token[slot0 + srow + 16];
        gA0 = xb + (size_t)tok0 * H_DIM + schunk;
        gA1 = xb + (size_t)tok1 * H_DIM + schunk;
        gBg = w_gate + (size_t)e * H_DIM * I_DIM + ci0;
        gBu = w_up   + (size_t)e * H_DIM * I_DIM + ci0;
        bstride = I_DIM;
    } else {
        int bb = b - 384;
        row0 = (bb >> 4) * 128;
        ci0 = (bb & 15) * 128;
        gA0 = xb + (size_t)(row0 + srow) * H_DIM + schunk;
        gA1 = gA0 + 16 * H_DIM;
        gBg = ws_gate + ci0;
        gBu = ws_up + ci0;
        bstride = IS_DIM;
    }
    int bcol = tid & 127, khalf = tid >> 7;

    f32x4 accg[4][4], accu[4][4];
#pragma unroll
    for (int i = 0; i < 4; i++)
#pragma unroll
        for (int j = 0; j < 4; j++)
#pragma unroll
            for (int r = 0; r < 4; r++) { accg[i][j][r] = 0.f; accu[i][j][r] = 0.f; }

    float rg[16], ru[16];

#define GU_LOADB(KK)                                                    \
    do {                                                                \
        size_t kb = (size_t)((KK) * 32 + khalf * 16);                   \
        _Pragma("unroll")                                               \
        for (int j = 0; j < 16; j++) {                                  \
            rg[j] = gBg[(kb + j) * bstride + bcol];                     \
            ru[j] = gBu[(kb + j) * bstride + bcol];                     \
        }                                                               \
    } while (0)

#define GU_GLLA(KK, BSEL)                                               \
    do {                                                                \
        int _k0 = (KK) * 32;                                            \
        unsigned short* _a = &lA[BSEL][aoff];                           \
        gll16(gA0 + _k0, _a);                                           \
        gll16(gA1 + _k0, _a + 16 * 32);                                 \
    } while (0)

#define GU_WRB(BSEL)                                                    \
    do {                                                                \
        uint4 u;                                                        \
        unsigned short* dg = &lBg[BSEL][bcol * 40 + khalf * 16];        \
        u.x = cvt2(rg[0], rg[1]);  u.y = cvt2(rg[2], rg[3]);            \
        u.z = cvt2(rg[4], rg[5]);  u.w = cvt2(rg[6], rg[7]);            \
        *reinterpret_cast<uint4*>(dg) = u;                              \
        u.x = cvt2(rg[8], rg[9]);  u.y = cvt2(rg[10], rg[11]);          \
        u.z = cvt2(rg[12], rg[13]); u.w = cvt2(rg[14], rg[15]);         \
        *reinterpret_cast<uint4*>(dg + 8) = u;                          \
        unsigned short* du = &lBu[BSEL][bcol * 40 + khalf * 16];        \
        u.x = cvt2(ru[0], ru[1]);  u.y = cvt2(ru[2], ru[3]);            \
        u.z = cvt2(ru[4], ru[5]);  u.w = cvt2(ru[6], ru[7]);            \
        *reinterpret_cast<uint4*>(du) = u;                              \
        u.x = cvt2(ru[8], ru[9]);  u.y = cvt2(ru[10], ru[11]);          \
        u.z = cvt2(ru[12], ru[13]); u.w = cvt2(ru[14], ru[15]);         \
        *reinterpret_cast<uint4*>(du + 8) = u;                          \
    } while (0)

    GU_GLLA(0, 0);
    GU_LOADB(0);
    __syncthreads();          // A(0) in LDS, B(0) in regs
    GU_WRB(0);
    __syncthreads();          // lB[0] visible
    for (int kk = 0; kk < 32; kk++) {
        int cur = kk & 1;
        if (kk < 31) { GU_GLLA(kk + 1, cur ^ 1); GU_LOADB(kk + 1); }
        bf16x8 af[4], bgf[4], buf2[4];
#pragma unroll
        for (int mi = 0; mi < 4; mi++)
            af[mi] = *reinterpret_cast<const bf16x8*>(
                &lA[cur][(wr * 64 + mi * 16 + (lane & 15)) * 32 + (lane >> 4) * 8]);
#pragma unroll
        for (int ni = 0; ni < 4; ni++) {
            int nn = (wc * 64 + ni * 16 + (lane & 15)) * 40 + (lane >> 4) * 8;
            bgf[ni] = *reinterpret_cast<const bf16x8*>(&lBg[cur][nn]);
            buf2[ni] = *reinterpret_cast<const bf16x8*>(&lBu[cur][nn]);
        }
#pragma unroll
        for (int mi = 0; mi < 4; mi++)
#pragma unroll
            for (int ni = 0; ni < 4; ni++) {
                accg[mi][ni] = __builtin_amdgcn_mfma_f32_16x16x32_bf16(af[mi], bgf[ni], accg[mi][ni], 0, 0, 0);
                accu[mi][ni] = __builtin_amdgcn_mfma_f32_16x16x32_bf16(af[mi], buf2[ni], accu[mi][ni], 0, 0, 0);
            }
        __syncthreads();      // done reading cur; drains loads for k+1
        if (kk < 31) {
            GU_WRB(cur ^ 1);
            __syncthreads();  // lB[k+1] visible
        }
    }
#undef GU_LOADB
#undef GU_GLLA
#undef GU_WRB

    int q = lane >> 4, cl = lane & 15;
    if (routed) {
#pragma unroll
        for (int mi = 0; mi < 4; mi++) {
#pragma unroll
            for (int r = 0; r < 4; r++) {
                int row = wr * 64 + mi * 16 + q * 4 + r;
                int token = pair_token[slot0 + row];
                float s = combine[token * E_NUM + e];
#pragma unroll
                for (int ni = 0; ni < 4; ni++) {
                    float g = accg[mi][ni][r], u = accu[mi][ni][r];
                    float a = g / (1.f + expf(-g)) * u * s;
                    act_s[(size_t)(slot0 + row) * I_DIM + ci0 + wc * 64 + ni * 16 + cl] = f2b(a);
                }
            }
        }
    } else {
#pragma unroll
        for (int mi = 0; mi < 4; mi++) {
#pragma unroll
            for (int ni = 0; ni < 4; ni++) {
                int col = ci0 + wc * 64 + ni * 16 + cl;
#pragma unroll
                for (int r = 0; r < 4; r++) {
                    int row = row0 + wr * 64 + mi * 16 + q * 4 + r;
                    float g = accg[mi][ni][r], u = accu[mi][ni][r];
                    float a = g / (1.f + expf(-g)) * u;
                    act_sh[(size_t)row * IS_DIM + col] = f2b(a);
                }
            }
        }
    }
}

// ================= fused down, direct-fp32 B =================
// blocks [0,768): routed | [768,1024): shared splitK=4
__global__ __launch_bounds__(256, 3)
void down_fused(const unsigned short* __restrict__ act_s,
                const float* __restrict__ w_down,
                const unsigned short* __restrict__ act_sh,
                const float* __restrict__ ws_down,
                const int* __restrict__ meta,
                float* __restrict__ pairpart,
                float* __restrict__ shpart) {
    int b = blockIdx.x;
    bool routed = b < 768;
    int tid = threadIdx.x, lane = tid & 63, w = tid >> 6;
    int wr = w >> 1, wc = w & 1;
    __shared__ __align__(16) unsigned short lA[2][128 * 32];
    __shared__ __align__(16) unsigned short lB[2][128 * 40];

    int srow = w * 32 + (lane >> 2);
    int schunk = (lane & 3) * 8;
    int aoff = (w * 32) * 32;

    const unsigned short* gA0;
    const float* gB;
    size_t ast;
    int kbase, n0, orow;
    float* outp;
    if (routed) {
        int tile = b >> 3;
        if (tile >= meta[0]) return;
        int e = meta[1 + tile];
        n0 = (b & 7) * 128;
        int slot0 = tile * 128;
        gA0 = act_s + (size_t)(slot0 + srow) * I_DIM + schunk;
        gB = w_down + (size_t)e * I_DIM * H_DIM + n0;
        ast = I_DIM; kbase = 0;
        outp = pairpart; orow = slot0;
    } else {
        int bb = b - 768;
        int mb = bb >> 5, nb = (bb >> 2) & 7, ks = bb & 3;
        int row0 = mb * 128;
        n0 = nb * 128;
        gA0 = act_sh + (size_t)(row0 + srow) * IS_DIM + schunk;
        gB = ws_down + n0;
        ast = IS_DIM; kbase = ks * 512;
        outp = shpart + ((size_t)ks << 20); orow = row0;
    }
    int bcol = tid & 127, khalf = tid >> 7;

    f32x4 acc[4][4];
#pragma unroll
    for (int i = 0; i < 4; i++)
#pragma unroll
        for (int j = 0; j < 4; j++)
#pragma unroll
            for (int r = 0; r < 4; r++) acc[i][j][r] = 0.f;

    float rb[16];

#define DN_LOADB(KK)                                                    \
    do {                                                                \
        size_t kb = (size_t)(kbase + (KK) * 32 + khalf * 16);           \
        _Pragma("unroll")                                               \
        for (int j = 0; j < 16; j++)                                    \
            rb[j] = gB[(kb + j) * H_DIM + bcol];                        \
    } while (0)

#define DN_GLLA(KK, BSEL)                                               \
    do {                                                                \
        size_t _k0 = (size_t)kbase + (size_t)(KK) * 32;                 \
        unsigned short* _a = &lA[BSEL][aoff];                           \
        gll16(gA0 + _k0, _a);                                           \
        gll16(gA0 + 16 * ast + _k0, _a + 16 * 32);                      \
    } while (0)

#define DN_WRB(BSEL)                                                    \
    do {                                                                \
        uint4 u;                                                        \
        unsigned short* d = &lB[BSEL][bcol * 40 + khalf * 16];          \
        u.x = cvt2(rb[0], rb[1]);  u.y = cvt2(rb[2], rb[3]);            \
        u.z = cvt2(rb[4], rb[5]);  u.w = cvt2(rb[6], rb[7]);            \
        *reinterpret_cast<uint4*>(d) = u;                               \
        u.x = cvt2(rb[8], rb[9]);  u.y = cvt2(rb[10], rb[11]);          \
        u.z = cvt2(rb[12], rb[13]); u.w = cvt2(rb[14], rb[15]);         \
        *reinterpret_cast<uint4*>(d + 8) = u;                           \
    } while (0)

    DN_GLLA(0, 0);
    DN_LOADB(0);
    __syncthreads();
    DN_WRB(0);
    __syncthreads();
    for (int kk = 0; kk < 16; kk++) {
        int cur = kk & 1;
        if (kk < 15) { DN_GLLA(kk + 1, cur ^ 1); DN_LOADB(kk + 1); }
        bf16x8 af[4], bf[4];
#pragma unroll
        for (int mi = 0; mi < 4; mi++)
            af[mi] = *reinterpret_cast<const bf16x8*>(
                &lA[cur][(wr * 64 + mi * 16 + (lane & 15)) * 32 + (lane >> 4) * 8]);
#pragma unroll
        for (int ni = 0; ni < 4; ni++)
            bf[ni] = *reinterpret_cast<const bf16x8*>(
                &lB[cur][(wc * 64 + ni * 16 + (lane & 15)) * 40 + (lane >> 4) * 8]);
#pragma unroll
        for (int mi = 0; mi < 4; mi++)
#pragma unroll
            for (int ni = 0; ni < 4; ni++)
                acc[mi][ni] = __builtin_amdgcn_mfma_f32_16x16x32_bf16(af[mi], bf[ni], acc[mi][ni], 0, 0, 0);
        __syncthreads();
        if (kk < 15) {
            DN_WRB(cur ^ 1);
            __syncthreads();
        }
    }
#undef DN_LOADB
#undef DN_GLLA
#undef DN_WRB

    int q = lane >> 4, cl = lane & 15;
#pragma unroll
    for (int mi = 0; mi < 4; mi++) {
#pragma unroll
        for (int ni = 0; ni < 4; ni++) {
            int col = n0 + wc * 64 + ni * 16 + cl;
#pragma unroll
            for (int r = 0; r < 4; r++) {
                int row = orow + wr * 64 + mi * 16 + q * 4 + r;
                outp[(size_t)row * H_DIM + col] = acc[mi][ni][r];
            }
        }
    }
}

// ---------------- final combine ----------------
__global__ void final_combine(const float* __restrict__ pairpart,
                              const float* __restrict__ shpart,
                              const int* __restrict__ slot_of,
                              float* __restrict__ out) {
    int t = blockIdx.x;
    int h = threadIdx.x * 4;
    float4 o = reinterpret_cast<const float4*>(shpart + (size_t)t * H_DIM + h)[0];
#pragma unroll
    for (int ks = 1; ks < 4; ks++) {
        float4 v = reinterpret_cast<const float4*>(shpart + ((size_t)ks << 20) + (size_t)t * H_DIM + h)[0];
        o.x += v.x; o.y += v.y; o.z += v.z; o.w += v.w;
    }
#pragma unroll
    for (int r = 0; r < 8; r++) {
        int s = slot_of[t * 8 + r];
        float4 v = reinterpret_cast<const float4*>(pairpart + (size_t)s * H_DIM + h)[0];
        o.x += v.x; o.y += v.y; o.z += v.z; o.w += v.w;
    }
    reinterpret_cast<float4*>(out + (size_t)t * H_DIM + h)[0] = o;
}

// ================= FALLBACK PATH (round-1 kernels, small ws) =================

__global__ void cvt_x_kernel(const float* __restrict__ x, unsigned short* __restrict__ xb) {
    int i = blockIdx.x * 256 + threadIdx.x;
    float4 v = reinterpret_cast<const float4*>(x)[i];
    uint2 o;
    o.x = (uint32_t)f2b(v.x) | ((uint32_t)f2b(v.y) << 16);
    o.y = (uint32_t)f2b(v.z) | ((uint32_t)f2b(v.w) << 16);
    reinterpret_cast<uint2*>(xb)[i] = o;
}

__global__ void routing_kernel(const float* __restrict__ x,
                               const float* __restrict__ gate_w,
                               const float* __restrict__ e_bias,
                               float* __restrict__ combine,
                               int* __restrict__ topk) {
    int t = blockIdx.x;
    routing_wave(x, gate_w, e_bias, combine, topk, t);
}

__global__ __launch_bounds__(256, 2)
void gateup_kernel(const unsigned short* __restrict__ xb,
                   const float* __restrict__ w_gate,
                   const float* __restrict__ w_up,
                   const float* __restrict__ ws_gate,
                   const float* __restrict__ ws_up,
                   const float* __restrict__ combine,
                   unsigned short* __restrict__ act) {
    int mb = blockIdx.x, cb = blockIdx.y;
    int row0 = mb * 128, c0 = cb * 128;
    const float *bg, *bu;
    int bstride, eidx;
    if (c0 < NCOL_R) {
        int e = c0 >> 9, ci = c0 & 511;
        bg = w_gate + (size_t)e * H_DIM * I_DIM + ci;
        bu = w_up   + (size_t)e * H_DIM * I_DIM + ci;
        bstride = I_DIM; eidx = e;
    } else {
        int ci = c0 - NCOL_R;
        bg = ws_gate + ci; bu = ws_up + ci;
        bstride = IS_DIM; eidx = -1;
    }
    __shared__ __align__(16) unsigned short lA[128*32];
    __shared__ __align__(16) unsigned short lBg[128*32];
    __shared__ __align__(16) unsigned short lBu[128*32];
    int tid = threadIdx.x, lane = tid & 63, w = tid >> 6;
    int wr = w >> 1, wc = w & 1;
    f32x4 accg[4][4], accu[4][4];
#pragma unroll
    for (int i = 0; i < 4; i++)
#pragma unroll
        for (int j = 0; j < 4; j++)
#pragma unroll
            for (int r = 0; r < 4; r++) { accg[i][j][r] = 0.f; accu[i][j][r] = 0.f; }
    int ar = tid >> 2, ak = (tid & 3) * 8;
    int bn = tid & 127, bkg = (tid >> 7) * 16;
    for (int kk = 0; kk < H_DIM / 32; kk++) {
        int k0 = kk * 32;
        __syncthreads();
        *reinterpret_cast<uint4*>(&lA[ar*32 + ak]) =
            *reinterpret_cast<const uint4*>(xb + (size_t)(row0 + ar) * H_DIM + k0 + ak);
        *reinterpret_cast<uint4*>(&lA[(ar+64)*32 + ak]) =
            *reinterpret_cast<const uint4*>(xb + (size_t)(row0 + ar + 64) * H_DIM + k0 + ak);
#pragma unroll
        for (int p = 0; p < 4; p++) {
            int kb = bkg + p * 4;
            const float* pg = bg + (size_t)(k0 + kb) * bstride + bn;
            uint2 dg;
            dg.x = (uint32_t)f2b(pg[0])         | ((uint32_t)f2b(pg[bstride])   << 16);
            dg.y = (uint32_t)f2b(pg[2*bstride]) | ((uint32_t)f2b(pg[3*bstride]) << 16);
            *reinterpret_cast<uint2*>(&lBg[bn*32 + kb]) = dg;
            const float* pu = bu + (size_t)(k0 + kb) * bstride + bn;
            uint2 du;
            du.x = (uint32_t)f2b(pu[0])         | ((uint32_t)f2b(pu[bstride])   << 16);
            du.y = (uint32_t)f2b(pu[2*bstride]) | ((uint32_t)f2b(pu[3*bstride]) << 16);
            *reinterpret_cast<uint2*>(&lBu[bn*32 + kb]) = du;
        }
        __syncthreads();
        bf16x8 af[4], bgf[4], buf2[4];
#pragma unroll
        for (int mi = 0; mi < 4; mi++)
            af[mi] = *reinterpret_cast<const bf16x8*>(&lA[(wr*64 + mi*16 + (lane & 15))*32 + (lane >> 4)*8]);
#pragma unroll
        for (int ni = 0; ni < 4; ni++) {
            int nn = (wc*64 + ni*16 + (lane & 15))*32 + (lane >> 4)*8;
            bgf[ni]  = *reinterpret_cast<const bf16x8*>(&lBg[nn]);
            buf2[ni] = *reinterpret_cast<const bf16x8*>(&lBu[nn]);
        }
#pragma unroll
        for (int mi = 0; mi < 4; mi++)
#pragma unroll
            for (int ni = 0; ni < 4; ni++) {
                accg[mi][ni] = __builtin_amdgcn_mfma_f32_16x16x32_bf16(af[mi], bgf[ni],  accg[mi][ni], 0, 0, 0);
                accu[mi][ni] = __builtin_amdgcn_mfma_f32_16x16x32_bf16(af[mi], buf2[ni], accu[mi][ni], 0, 0, 0);
            }
    }
    int q = lane >> 4, cl = lane & 15;
#pragma unroll
    for (int mi = 0; mi < 4; mi++) {
#pragma unroll
        for (int ni = 0; ni < 4; ni++) {
            int colg = c0 + wc*64 + ni*16 + cl;
#pragma unroll
            for (int r = 0; r < 4; r++) {
                int row = row0 + wr*64 + mi*16 + q*4 + r;
                float g = accg[mi][ni][r], u = accu[mi][ni][r];
                float a = g / (1.f + expf(-g)) * u;
                float s = (eidx >= 0) ? combine[row * E_NUM + eidx] : 1.0f;
                act[(size_t)row * NCOL_T + colg] = f2b(a * s);
            }
        }
    }
}

__global__ __launch_bounds__(256, 2)
void down_kernel(const unsigned short* __restrict__ act,
                 const float* __restrict__ w_down,
                 const float* __restrict__ ws_down,
                 float* __restrict__ partials) {
    int mb = blockIdx.x, nb = blockIdx.y, ks = blockIdx.z;
    int row0 = mb * 128, n0 = nb * 128;
    __shared__ __align__(16) unsigned short lA[128*32];
    __shared__ __align__(16) unsigned short lB[128*32];
    int tid = threadIdx.x, lane = tid & 63, w = tid >> 6;
    int wr = w >> 1, wc = w & 1;
    f32x4 acc[4][4];
#pragma unroll
    for (int i = 0; i < 4; i++)
#pragma unroll
        for (int j = 0; j < 4; j++)
#pragma unroll
            for (int r = 0; r < 4; r++) acc[i][j][r] = 0.f;
    int ar = tid >> 2, ak = (tid & 3) * 8;
    int bn = tid & 127, bkg = (tid >> 7) * 16;
    for (int kk = 0; kk < 144; kk++) {
        int k0 = ks * 4608 + kk * 32;
        const float* bb = (k0 < NCOL_R) ? (w_down + (size_t)k0 * H_DIM)
                                        : (ws_down + (size_t)(k0 - NCOL_R) * H_DIM);
        __syncthreads();
        *reinterpret_cast<uint4*>(&lA[ar*32 + ak]) =
            *reinterpret_cast<const uint4*>(act + (size_t)(row0 + ar) * NCOL_T + k0 + ak);
        *reinterpret_cast<uint4*>(&lA[(ar+64)*32 + ak]) =
            *reinterpret_cast<const uint4*>(act + (size_t)(row0 + ar + 64) * NCOL_T + k0 + ak);
#pragma unroll
        for (int p = 0; p < 4; p++) {
            int kb = bkg + p * 4;
            const float* pb = bb + (size_t)kb * H_DIM + n0 + bn;
            uint2 d;
            d.x = (uint32_t)f2b(pb[0])       | ((uint32_t)f2b(pb[H_DIM])   << 16);
            d.y = (uint32_t)f2b(pb[2*H_DIM]) | ((uint32_t)f2b(pb[3*H_DIM]) << 16);
            *reinterpret_cast<uint2*>(&lB[bn*32 + kb]) = d;
        }
        __syncthreads();
        bf16x8 af[4], bf[4];
#pragma unroll
        for (int mi = 0; mi < 4; mi++)
            af[mi] = *reinterpret_cast<const bf16x8*>(&lA[(wr*64 + mi*16 + (lane & 15))*32 + (lane >> 4)*8]);
#pragma unroll
        for (int ni = 0; ni < 4; ni++)
            bf[ni] = *reinterpret_cast<const bf16x8*>(&lB[(wc*64 + ni*16 + (lane & 15))*32 + (lane >> 4)*8]);
#pragma unroll
        for (int mi = 0; mi < 4; mi++)
#pragma unroll
            for (int ni = 0; ni < 4; ni++)
                acc[mi][ni] = __builtin_amdgcn_mfma_f32_16x16x32_bf16(af[mi], bf[ni], acc[mi][ni], 0, 0, 0);
    }
    float* pout = partials + ((size_t)ks << 20);
    int q = lane >> 4, cl = lane & 15;
#pragma unroll
    for (int mi = 0; mi < 4; mi++) {
#pragma unroll
        for (int ni = 0; ni < 4; ni++) {
            int col = n0 + wc*64 + ni*16 + cl;
#pragma unroll
            for (int r = 0; r < 4; r++) {
                int row = row0 + wr*64 + mi*16 + q*4 + r;
                pout[(size_t)row * H_DIM + col] = acc[mi][ni][r];
            }
        }
    }
}

__global__ void reduce_kernel(const float* __restrict__ p, float* __restrict__ out) {
    int i = blockIdx.x * 256 + threadIdx.x;
    float4 a = reinterpret_cast<const float4*>(p)[i];
    float4 b = reinterpret_cast<const float4*>(p + (size_t)1048576)[i];
    float4 c = reinterpret_cast<const float4*>(p + (size_t)2097152)[i];
    float4 d = reinterpret_cast<const float4*>(p + (size_t)3145728)[i];
    float4 o;
    o.x = a.x + b.x + c.x + d.x;
    o.y = a.y + b.y + c.y + d.y;
    o.z = a.z + b.z + c.z + d.z;
    o.w = a.w + b.w + c.w + d.w;
    reinterpret_cast<float4*>(out)[i] = o;
}

extern "C" void kernel_launch(void* const* d_in, const int* in_sizes, int n_in,
                              void* d_out, int out_size, void* d_ws, size_t ws_size,
                              hipStream_t stream) {
    const float* x       = (const float*)d_in[0];
    const float* gate_w  = (const float*)d_in[1];
    const float* e_bias  = (const float*)d_in[2];
    const float* w_gate  = (const float*)d_in[3];
    const float* w_up    = (const float*)d_in[4];
    const float* w_down  = (const float*)d_in[5];
    const float* ws_gate = (const float*)d_in[6];
    const float* ws_up   = (const float*)d_in[7];
    const float* ws_down = (const float*)d_in[8];
    float* out = (float*)d_out;

    char* ws = (char*)d_ws;
    bool fast = ws_size >= 170000384ull;   // ws_size constant across calls -> capture-safe branch

    if (fast) {
        float* combine      = (float*)(ws);                       // 131072
        int*   topk         = (int*)(ws + 131072);                // 32768
        int*   meta         = (int*)(ws + 163840);                // 512
        int*   pair_token   = (int*)(ws + 164352);                // 49152
        int*   slot_of      = (int*)(ws + 213504);                // 32768
        unsigned short* xb  = (unsigned short*)(ws + 262144);     // 2 MB
        unsigned short* act_s  = (unsigned short*)(ws + 2359296);    // 12.6 MB
        unsigned short* act_sh = (unsigned short*)(ws + 14942208);   // 4 MB
        float* pairpart     = (float*)(ws + 19136512);               // 50.33 MB
        float* shpart       = (float*)(ws + 69468160);               // 16 MB, ends 86245376

        prep1_kernel<<<512, 256, 0, stream>>>(x, gate_w, e_bias, xb, combine, topk);
        listbuild_kernel<<<1, 1024, 0, stream>>>(topk, meta, pair_token, slot_of);
        gateup_fused<<<512, 256, 0, stream>>>(xb, w_gate, w_up, ws_gate, ws_up,
                                              combine, pair_token, meta, act_s, act_sh);
        down_fused<<<1024, 256, 0, stream>>>(act_s, w_down, act_sh, ws_down, meta,
                                             pairpart, shpart);
        final_combine<<<1024, 256, 0, stream>>>(pairpart, shpart, slot_of, out);
    } else {
        float* combine     = (float*)(ws);
        int*   topk        = (int*)(ws + 131072);
        unsigned short* xb = (unsigned short*)(ws + 262144);
        unsigned short* act= (unsigned short*)(ws + 2359296);
        float* partials    = (float*)(ws + 40108032);

        cvt_x_kernel<<<1024, 256, 0, stream>>>(x, xb);
        routing_kernel<<<1024, 64, 0, stream>>>(x, gate_w, e_bias, combine, topk);
        gateup_kernel<<<dim3(8, 144), 256, 0, stream>>>(xb, w_gate, w_up, ws_gate, ws_up, combine, act);
        down_kernel<<<dim3(8, 8, 4), 256, 0, stream>>>(act, w_down, ws_down, partials);
        reduce_kernel<<<1024, 256, 0, stream>>>(partials, out);
    }
}